// Round 6
// baseline (147.671 us; speedup 1.0000x reference)
//
#include <hip/hip_runtime.h>
#include <math.h>

#define B_ 4
#define L_ 4096
#define D_ 128
#define N_ 16
#define DT_ 0.1f
#define CHUNK_ 32
#define NC_ 128   // L_/CHUNK_

// ws layout in floats:
#define ABAR_OFF 0                        // abar [B][L][N]
#define COEF_OFF 262144                   // coef [B][L][N]
#define CC_OFF   524288                   // Cc   [B][L][N]
#define HL_OFF   786432                   // hL [B][NC][D][N]
#define H0_OFF   1835008                  // h0 [B][NC][D][N]
#define P_OFF    2883584                  // P  [B][NC][N]
#define W_OFF    2891776                  // w  [B][L][N]  (C*Pcum)
#define YP_OFF   3153920                  // y_part [B][L][D]

// K1: fused projections + discretization. 512 blocks x 256 threads.
// tile = bid>>1 (64 rows), type = bid&1: type0 -> Bp+delta -> abar/coef; type1 -> Cc.
__global__ __launch_bounds__(256) void k1_proj(const float* __restrict__ x,
                                               const float* __restrict__ A,
                                               const float* __restrict__ Wb,
                                               const float* __restrict__ bb,
                                               const float* __restrict__ Wc,
                                               const float* __restrict__ bc,
                                               const float* __restrict__ Wd,
                                               const float* __restrict__ bd,
                                               float* __restrict__ ws) {
    __shared__ float xs[64][129];
    __shared__ float proj[64][18];

    float* abar_o = ws + ABAR_OFF;
    float* coef_o = ws + COEF_OFF;
    float* cc_o   = ws + CC_OFF;

    const int t = threadIdx.x;
    const int bt = blockIdx.x & 1;
    const size_t row0 = (size_t)(blockIdx.x >> 1) * 64;

    const float4* xg = (const float4*)(x + row0 * 128);
    for (int i = t; i < 2048; i += 256) {
        float4 v = xg[i];
        int r = i >> 5;
        int c0 = (i & 31) << 2;
        xs[r][c0]     = v.x;
        xs[r][c0 + 1] = v.y;
        xs[r][c0 + 2] = v.z;
        xs[r][c0 + 3] = v.w;
    }
    __syncthreads();

    const int w = __builtin_amdgcn_readfirstlane(t >> 6);
    const int lane = t & 63;

    const float* cbase = (bt == 0 ? Wb : Wc) + (size_t)w * 4 * 128;
    float a0 = 0.f, a1 = 0.f, a2 = 0.f, a3 = 0.f;
#pragma unroll 8
    for (int k = 0; k < 128; ++k) {
        float xv = xs[lane][k];
        a0 = fmaf(xv, cbase[k],       a0);
        a1 = fmaf(xv, cbase[128 + k], a1);
        a2 = fmaf(xv, cbase[256 + k], a2);
        a3 = fmaf(xv, cbase[384 + k], a3);
    }
    proj[lane][w * 4]     = a0;
    proj[lane][w * 4 + 1] = a1;
    proj[lane][w * 4 + 2] = a2;
    proj[lane][w * 4 + 3] = a3;
    if (bt == 0 && w == 3) {
        float ad = 0.f;
#pragma unroll 8
        for (int k = 0; k < 128; ++k) ad = fmaf(xs[lane][k], Wd[k], ad);
        proj[lane][16] = ad;
    }
    __syncthreads();

    const int r = t & 63;
    const int g = t >> 6;
    const int n0 = g * 4;
    const size_t orow = (row0 + (size_t)r) * 16 + n0;

    if (bt == 0) {
        float zd = proj[r][16] + bd[0];
        float sp = fmaxf(zd, 0.f) + log1pf(expf(-fabsf(zd)));  // stable softplus
        float delta = sp + DT_;
        float4 ab4, cf4;
        { float Bp = proj[r][n0]     + bb[n0];     float dA = delta * A[n0];
          ab4.x = expf(dA); cf4.x = (1.f - expf(-dA)) * delta * Bp; }
        { float Bp = proj[r][n0 + 1] + bb[n0 + 1]; float dA = delta * A[n0 + 1];
          ab4.y = expf(dA); cf4.y = (1.f - expf(-dA)) * delta * Bp; }
        { float Bp = proj[r][n0 + 2] + bb[n0 + 2]; float dA = delta * A[n0 + 2];
          ab4.z = expf(dA); cf4.z = (1.f - expf(-dA)) * delta * Bp; }
        { float Bp = proj[r][n0 + 3] + bb[n0 + 3]; float dA = delta * A[n0 + 3];
          ab4.w = expf(dA); cf4.w = (1.f - expf(-dA)) * delta * Bp; }
        *(float4*)(abar_o + orow) = ab4;
        *(float4*)(coef_o + orow) = cf4;
    } else {
        float4 cv4;
        cv4.x = proj[r][n0]     + bc[n0];
        cv4.y = proj[r][n0 + 1] + bc[n0 + 1];
        cv4.z = proj[r][n0 + 2] + bc[n0 + 2];
        cv4.w = proj[r][n0 + 3] + bc[n0 + 3];
        *(float4*)(cc_o + orow) = cv4;
    }
}

// K2a': per-chunk local scan producing hL, P, y_local, w = C*Pcum.
// gw = [b:2][dgrp:3][c:7]; lane = ng*16+dq; d = dgrp*16+dq; n = ng*4..+3.
__global__ __launch_bounds__(256, 4) void k2a_chunk(const float* __restrict__ x,
                                                    float* __restrict__ ws) {
    const float* abar = ws + ABAR_OFF;
    const float* coef = ws + COEF_OFF;
    const float* cc   = ws + CC_OFF;
    float* hL = ws + HL_OFF;
    float* Pp = ws + P_OFF;
    float* wo = ws + W_OFF;
    float* yp = ws + YP_OFF;

    const int gw = blockIdx.x * 4 + (threadIdx.x >> 6);
    const int lane = threadIdx.x & 63;
    const int b = gw >> 10;
    const int dgrp = (gw >> 7) & 7;
    const int c = gw & 127;
    const int ng = lane >> 4;
    const int dq = lane & 15;
    const int d = dgrp * 16 + dq;
    const int l0 = c * CHUNK_;
    const float* pa = abar + ((size_t)b * L_ + l0) * 16 + ng * 4;
    const float* pc = coef + ((size_t)b * L_ + l0) * 16 + ng * 4;
    const float* pC = cc   + ((size_t)b * L_ + l0) * 16 + ng * 4;
    const float* px = x + ((size_t)b * L_ + l0) * 128 + d;
    float* pw = wo + ((size_t)b * L_ + l0) * 16 + ng * 4;
    float* py = yp + ((size_t)b * L_ + l0) * 128 + d;

    float h0v = 0.f, h1v = 0.f, h2v = 0.f, h3v = 0.f;
    float P0 = 1.f, P1 = 1.f, P2 = 1.f, P3 = 1.f;
    const bool wlane = (dgrp == 0) && (dq == 0);

    float4 a4 = *(const float4*)pa;
    float4 c4 = *(const float4*)pc;
    float4 C4 = *(const float4*)pC;
    float xv = px[0];
#pragma unroll 8
    for (int t = 0; t < CHUNK_; ++t) {
        float4 an, cn, Cn;
        float xn;
        if (t < CHUNK_ - 1) {
            an = *(const float4*)(pa + (t + 1) * 16);
            cn = *(const float4*)(pc + (t + 1) * 16);
            Cn = *(const float4*)(pC + (t + 1) * 16);
            xn = px[(t + 1) * 128];
        }
        P0 *= a4.x; P1 *= a4.y; P2 *= a4.z; P3 *= a4.w;
        h0v = fmaf(a4.x, h0v, c4.x * xv);
        h1v = fmaf(a4.y, h1v, c4.y * xv);
        h2v = fmaf(a4.z, h2v, c4.z * xv);
        h3v = fmaf(a4.w, h3v, c4.w * xv);
        if (wlane) {
            *(float4*)(pw + t * 16) = make_float4(C4.x * P0, C4.y * P1,
                                                  C4.z * P2, C4.w * P3);
        }
        float yv = h0v * C4.x + h1v * C4.y + h2v * C4.z + h3v * C4.w;
        yv += __shfl_xor(yv, 16);
        yv += __shfl_xor(yv, 32);
        if (ng == 0) py[t * 128] = yv;
        if (t < CHUNK_ - 1) { a4 = an; c4 = cn; C4 = Cn; xv = xn; }
    }

    *(float4*)(hL + (((size_t)(b * NC_ + c)) * 128 + d) * 16 + ng * 4) =
        make_float4(h0v, h1v, h2v, h3v);
    if (dq == 0) {
        *(float4*)(Pp + ((size_t)(b * NC_ + c)) * 16 + ng * 4) =
            make_float4(P0, P1, P2, P3);
    }
}

// K2b: cross-chunk combine. 8192 threads = (b, d, n); serial over 127 chunk steps.
__global__ __launch_bounds__(256, 4) void k2b_combine(float* __restrict__ ws) {
    const float* hL = ws + HL_OFF;
    const float* Pp = ws + P_OFF;
    float* h0 = ws + H0_OFF;
    const int tid = blockIdx.x * 256 + threadIdx.x;  // 0..8191
    const int b = tid >> 11;
    const int dn = tid & 2047;
    const int n = tid & 15;

    const float* hp = hL + (size_t)b * NC_ * 2048 + dn;
    const float* pp = Pp + (size_t)b * NC_ * 16 + n;
    float* op = h0 + (size_t)b * NC_ * 2048 + dn;

    float h = 0.f;
    op[0] = 0.f;
#pragma unroll 8
    for (int c = 0; c < NC_ - 1; ++c) {
        float hl = hp[(size_t)c * 2048];
        float p  = pp[(size_t)c * 16];
        h = fmaf(p, h, hl);
        op[(size_t)(c + 1) * 2048] = h;
    }
}

// K2c': rank-16 correction: y = y_part + w . h0. Block = (b, chunk); 512 blocks.
// Stages h0 (8KB, padded) + w rows (2KB) in LDS; thread -> (t = thr>>3, 16 d's).
__global__ __launch_bounds__(256, 4) void k2c_update(const float* __restrict__ ws,
                                                     float* __restrict__ y) {
    __shared__ float h0s[128][17];
    __shared__ float wcs[32][17];

    const int blk = blockIdx.x;        // b*NC + c
    const int b = blk >> 7;
    const int c = blk & 127;
    const int t = threadIdx.x;

    const float4* h0g = (const float4*)(ws + H0_OFF + (size_t)blk * 2048);
    for (int i = t; i < 512; i += 256) {
        float4 v = h0g[i];
        int d = i >> 2, n0 = (i & 3) << 2;
        h0s[d][n0] = v.x; h0s[d][n0 + 1] = v.y;
        h0s[d][n0 + 2] = v.z; h0s[d][n0 + 3] = v.w;
    }
    const float4* wg = (const float4*)(ws + W_OFF + ((size_t)b * L_ + c * CHUNK_) * 16);
    for (int i = t; i < 128; i += 256) {
        float4 v = wg[i];
        int tt = i >> 2, n0 = (i & 3) << 2;
        wcs[tt][n0] = v.x; wcs[tt][n0 + 1] = v.y;
        wcs[tt][n0 + 2] = v.z; wcs[tt][n0 + 3] = v.w;
    }
    __syncthreads();

    const int tt = t >> 3;             // 0..31 (timestep in chunk)
    const int dblk = (t & 7) << 4;     // 0..112 (16 d's per thread)

    const float w0 = wcs[tt][0],  w1 = wcs[tt][1],  w2 = wcs[tt][2],  w3 = wcs[tt][3];
    const float w4 = wcs[tt][4],  w5 = wcs[tt][5],  w6 = wcs[tt][6],  w7 = wcs[tt][7];
    const float w8 = wcs[tt][8],  w9 = wcs[tt][9],  wA = wcs[tt][10], wB = wcs[tt][11];
    const float wC = wcs[tt][12], wD = wcs[tt][13], wE = wcs[tt][14], wF = wcs[tt][15];

    const size_t rowoff = ((size_t)b * L_ + c * CHUNK_ + tt) * 128 + dblk;
    const float4* yp4 = (const float4*)(ws + YP_OFF + rowoff);
    float4* yo4 = (float4*)(y + rowoff);

#pragma unroll
    for (int q = 0; q < 4; ++q) {
        float4 acc = yp4[q];
        float* ap = (float*)&acc;
#pragma unroll
        for (int j = 0; j < 4; ++j) {
            const float* hr = h0s[dblk + q * 4 + j];
            float s = ap[j];
            s = fmaf(w0, hr[0],  s); s = fmaf(w1, hr[1],  s);
            s = fmaf(w2, hr[2],  s); s = fmaf(w3, hr[3],  s);
            s = fmaf(w4, hr[4],  s); s = fmaf(w5, hr[5],  s);
            s = fmaf(w6, hr[6],  s); s = fmaf(w7, hr[7],  s);
            s = fmaf(w8, hr[8],  s); s = fmaf(w9, hr[9],  s);
            s = fmaf(wA, hr[10], s); s = fmaf(wB, hr[11], s);
            s = fmaf(wC, hr[12], s); s = fmaf(wD, hr[13], s);
            s = fmaf(wE, hr[14], s); s = fmaf(wF, hr[15], s);
            ap[j] = s;
        }
        yo4[q] = acc;
    }
}

extern "C" void kernel_launch(void* const* d_in, const int* in_sizes, int n_in,
                              void* d_out, int out_size, void* d_ws, size_t ws_size,
                              hipStream_t stream) {
    const float* x  = (const float*)d_in[0];
    const float* A  = (const float*)d_in[1];
    const float* Wb = (const float*)d_in[2];
    const float* bb = (const float*)d_in[3];
    const float* Wc = (const float*)d_in[4];
    const float* bc = (const float*)d_in[5];
    const float* Wd = (const float*)d_in[6];
    const float* bd = (const float*)d_in[7];
    float* ws = (float*)d_ws;
    float* y  = (float*)d_out;

    k1_proj<<<512, 256, 0, stream>>>(x, A, Wb, bb, Wc, bc, Wd, bd, ws);
    k2a_chunk<<<1024, 256, 0, stream>>>(x, ws);
    k2b_combine<<<32, 256, 0, stream>>>(ws);
    k2c_update<<<512, 256, 0, stream>>>(ws, y);
}

// Round 7
// 131.156 us; speedup vs baseline: 1.1259x; 1.1259x over previous
//
#include <hip/hip_runtime.h>
#include <math.h>

#define B_ 4
#define L_ 4096
#define D_ 128
#define N_ 16
#define DT_ 0.1f
#define CHUNK_ 32
#define NC_ 128   // L_/CHUNK_

// ws layout (floats):
#define HL_OFF 0                        // hL [B][NC][D][N]  1048576
#define H0_OFF 1048576                  // h0 [B][NC][D][N]  1048576
#define P_OFF  2097152                  // P  [B][NC][N]     8192
#define W_OFF  2105344                  // w  [B][L][N]      262144  (C*Pcum)
// total 2367488 floats ~= 9.5 MB

// Kernel A: fused projection + discretization + chunk-local scan.
// Block = (b, chunk c): 512 blocks x 256 threads.
// Phase 1: proj[32 rows][33 outs]; thread = (r=lane&31, oh=lane>>5), wave w
//   owns out-quad ob = 8w+4oh; W read as broadcast vector loads (L1-resident).
// Phase 1.5: delta (softplus), cumsum(delta), abar/coef/C into LDS,
//   w = C*exp(A_n * S_r) and chunk product P = exp(A_n * S_31) closed-form.
// Phase 2: 32-step scan in regs; thread = (dd=t>>2 -> d in {dd, dd+64}, nq=t&3);
//   y_local written straight to d_out; hL written for the combine.
__global__ __launch_bounds__(256) void kA_fused(const float* __restrict__ x,
                                                const float* __restrict__ A,
                                                const float* __restrict__ Wb,
                                                const float* __restrict__ bb,
                                                const float* __restrict__ Wc,
                                                const float* __restrict__ bc,
                                                const float* __restrict__ Wd,
                                                const float* __restrict__ bd,
                                                float* __restrict__ ws,
                                                float* __restrict__ y) {
    __shared__ float xs[32][132];
    __shared__ float proj[32][34];
    __shared__ float delta_s[32];
    __shared__ float Ssum[32];
    __shared__ float a_s[32][16];
    __shared__ float c_s[32][16];
    __shared__ float C_s[32][16];

    const int t = threadIdx.x;
    const int blk = blockIdx.x;          // b*NC + c
    const int b = blk >> 7;
    const int c = blk & 127;
    const int l0 = c * CHUNK_;

    // stage x chunk [32][128], coalesced
    const float4* xg = (const float4*)(x + ((size_t)b * L_ + l0) * 128);
#pragma unroll
    for (int i = t; i < 1024; i += 256) {
        float4 v = xg[i];
        int r = i >> 5, c4 = (i & 31) << 2;
        xs[r][c4] = v.x; xs[r][c4 + 1] = v.y;
        xs[r][c4 + 2] = v.z; xs[r][c4 + 3] = v.w;
    }
    __syncthreads();

    // phase 1: projections
    {
        const int wv = t >> 6;
        const int lane = t & 63;
        const int r = lane & 31;
        const int oh = lane >> 5;
        const int ob = wv * 8 + oh * 4;   // 0,4,...,28
        const float* wp = (ob < 16) ? (Wb + (size_t)ob * 128)
                                    : (Wc + (size_t)(ob - 16) * 128);
        const bool do32 = (wv == 0) && (oh == 0);
        float a0 = 0.f, a1 = 0.f, a2 = 0.f, a3 = 0.f, ad = 0.f;
#pragma unroll 4
        for (int k4 = 0; k4 < 32; ++k4) {
            float4 xv = *(const float4*)&xs[r][k4 * 4];
            float4 w0 = *(const float4*)(wp + k4 * 4);
            float4 w1 = *(const float4*)(wp + 128 + k4 * 4);
            float4 w2 = *(const float4*)(wp + 256 + k4 * 4);
            float4 w3 = *(const float4*)(wp + 384 + k4 * 4);
            a0 = fmaf(xv.x, w0.x, a0); a0 = fmaf(xv.y, w0.y, a0);
            a0 = fmaf(xv.z, w0.z, a0); a0 = fmaf(xv.w, w0.w, a0);
            a1 = fmaf(xv.x, w1.x, a1); a1 = fmaf(xv.y, w1.y, a1);
            a1 = fmaf(xv.z, w1.z, a1); a1 = fmaf(xv.w, w1.w, a1);
            a2 = fmaf(xv.x, w2.x, a2); a2 = fmaf(xv.y, w2.y, a2);
            a2 = fmaf(xv.z, w2.z, a2); a2 = fmaf(xv.w, w2.w, a2);
            a3 = fmaf(xv.x, w3.x, a3); a3 = fmaf(xv.y, w3.y, a3);
            a3 = fmaf(xv.z, w3.z, a3); a3 = fmaf(xv.w, w3.w, a3);
            if (do32) {
                float4 w4 = *(const float4*)(Wd + k4 * 4);
                ad = fmaf(xv.x, w4.x, ad); ad = fmaf(xv.y, w4.y, ad);
                ad = fmaf(xv.z, w4.z, ad); ad = fmaf(xv.w, w4.w, ad);
            }
        }
        proj[r][ob] = a0; proj[r][ob + 1] = a1;
        proj[r][ob + 2] = a2; proj[r][ob + 3] = a3;
        if (do32) proj[r][32] = ad;
    }
    __syncthreads();

    // delta per row
    if (t < 32) {
        float z = proj[t][32] + bd[0];
        float sp = fmaxf(z, 0.f) + log1pf(expf(-fabsf(z)));  // stable softplus
        delta_s[t] = sp + DT_;
    }
    __syncthreads();
    if (t == 0) {
        float s = 0.f;
        for (int r = 0; r < 32; ++r) { s += delta_s[r]; Ssum[r] = s; }
    }
    __syncthreads();

    // discretize + w = C * Pcum (closed form via exp(A*S))
    {
        float* wglob = ws + W_OFF + ((size_t)b * L_ + l0) * 16;
#pragma unroll
        for (int p = t; p < 512; p += 256) {
            int r = p >> 4, n = p & 15;
            float An = A[n];
            float delta = delta_s[r];
            float Bp = proj[r][n] + bb[n];
            float Cv = proj[r][16 + n] + bc[n];
            float dA = delta * An;
            a_s[r][n] = expf(dA);
            c_s[r][n] = (1.f - expf(-dA)) * delta * Bp;
            C_s[r][n] = Cv;
            wglob[p] = Cv * expf(An * Ssum[r]);
        }
        if (t < 16) {
            ws[P_OFF + (size_t)blk * 16 + t] = expf(A[t] * Ssum[31]);
        }
    }
    __syncthreads();

    // phase 2: chunk-local scan
    const int dd = t >> 2;   // 0..63 -> d in {dd, dd+64}
    const int nq = t & 3;
    float h0v = 0.f, h1v = 0.f, h2v = 0.f, h3v = 0.f;
    float g0v = 0.f, g1v = 0.f, g2v = 0.f, g3v = 0.f;
    float* yout = y + ((size_t)b * L_ + l0) * 128;
#pragma unroll 4
    for (int tt = 0; tt < 32; ++tt) {
        float4 av = *(const float4*)&a_s[tt][nq * 4];
        float4 cv = *(const float4*)&c_s[tt][nq * 4];
        float4 Cv = *(const float4*)&C_s[tt][nq * 4];
        float x0 = xs[tt][dd];
        float x1 = xs[tt][dd + 64];
        h0v = fmaf(av.x, h0v, cv.x * x0);
        h1v = fmaf(av.y, h1v, cv.y * x0);
        h2v = fmaf(av.z, h2v, cv.z * x0);
        h3v = fmaf(av.w, h3v, cv.w * x0);
        g0v = fmaf(av.x, g0v, cv.x * x1);
        g1v = fmaf(av.y, g1v, cv.y * x1);
        g2v = fmaf(av.z, g2v, cv.z * x1);
        g3v = fmaf(av.w, g3v, cv.w * x1);
        float y0 = h0v * Cv.x;
        y0 = fmaf(h1v, Cv.y, y0); y0 = fmaf(h2v, Cv.z, y0); y0 = fmaf(h3v, Cv.w, y0);
        float y1 = g0v * Cv.x;
        y1 = fmaf(g1v, Cv.y, y1); y1 = fmaf(g2v, Cv.z, y1); y1 = fmaf(g3v, Cv.w, y1);
        y0 += __shfl_xor(y0, 1); y0 += __shfl_xor(y0, 2);
        y1 += __shfl_xor(y1, 1); y1 += __shfl_xor(y1, 2);
        if (nq == 0) {
            yout[tt * 128 + dd] = y0;
            yout[tt * 128 + dd + 64] = y1;
        }
    }
    // write hL (contiguous by t)
    float* hL = ws + HL_OFF + (size_t)blk * 2048;
    *(float4*)(hL + dd * 16 + nq * 4) = make_float4(h0v, h1v, h2v, h3v);
    *(float4*)(hL + (dd + 64) * 16 + nq * 4) = make_float4(g0v, g1v, g2v, g3v);
}

// Kernel B: cross-chunk combine. 8192 threads = (b, d, n); serial 127 steps.
__global__ __launch_bounds__(256, 4) void kB_combine(float* __restrict__ ws) {
    const float* hL = ws + HL_OFF;
    const float* Pp = ws + P_OFF;
    float* h0 = ws + H0_OFF;
    const int tid = blockIdx.x * 256 + threadIdx.x;  // 0..8191
    const int b = tid >> 11;
    const int dn = tid & 2047;
    const int n = tid & 15;

    const float* hp = hL + (size_t)b * NC_ * 2048 + dn;
    const float* pp = Pp + (size_t)b * NC_ * 16 + n;
    float* op = h0 + (size_t)b * NC_ * 2048 + dn;

    float h = 0.f;
    op[0] = 0.f;
#pragma unroll 8
    for (int c = 0; c < NC_ - 1; ++c) {
        float hl = hp[(size_t)c * 2048];
        float p  = pp[(size_t)c * 16];
        h = fmaf(p, h, hl);
        op[(size_t)(c + 1) * 2048] = h;
    }
}

// Kernel C: rank-16 correction in-place: y += w . h0.
// Block = (b, chunk): 512 blocks x 256 threads; thread = (d = t&127, rh = t>>7).
// h0[d][0..15] in registers; w row broadcast from LDS.
__global__ __launch_bounds__(256, 4) void kC_update(const float* __restrict__ ws,
                                                    float* __restrict__ y) {
    __shared__ float w_s[32][16];
    const int blk = blockIdx.x;
    const int b = blk >> 7;
    const int c = blk & 127;
    const int t = threadIdx.x;

    if (t < 128) {
        float4 v = ((const float4*)(ws + W_OFF + ((size_t)b * L_ + c * CHUNK_) * 16))[t];
        int tt = t >> 2, n0 = (t & 3) << 2;
        w_s[tt][n0] = v.x; w_s[tt][n0 + 1] = v.y;
        w_s[tt][n0 + 2] = v.z; w_s[tt][n0 + 3] = v.w;
    }
    __syncthreads();

    const int d = t & 127;
    const int rh = t >> 7;
    const float* h0p = ws + H0_OFF + ((size_t)blk * 128 + d) * 16;
    const float4 ha = *(const float4*)h0p;
    const float4 hb = *(const float4*)(h0p + 4);
    const float4 hc = *(const float4*)(h0p + 8);
    const float4 hd = *(const float4*)(h0p + 12);

    float* yp = y + ((size_t)b * L_ + c * CHUNK_ + rh * 16) * 128 + d;
#pragma unroll
    for (int i = 0; i < 16; ++i) {
        const int tt = rh * 16 + i;
        float4 wa = *(const float4*)&w_s[tt][0];
        float4 wb4 = *(const float4*)&w_s[tt][4];
        float4 wc4 = *(const float4*)&w_s[tt][8];
        float4 wd4 = *(const float4*)&w_s[tt][12];
        float s = yp[i * 128];
        s = fmaf(wa.x, ha.x, s); s = fmaf(wa.y, ha.y, s);
        s = fmaf(wa.z, ha.z, s); s = fmaf(wa.w, ha.w, s);
        s = fmaf(wb4.x, hb.x, s); s = fmaf(wb4.y, hb.y, s);
        s = fmaf(wb4.z, hb.z, s); s = fmaf(wb4.w, hb.w, s);
        s = fmaf(wc4.x, hc.x, s); s = fmaf(wc4.y, hc.y, s);
        s = fmaf(wc4.z, hc.z, s); s = fmaf(wc4.w, hc.w, s);
        s = fmaf(wd4.x, hd.x, s); s = fmaf(wd4.y, hd.y, s);
        s = fmaf(wd4.z, hd.z, s); s = fmaf(wd4.w, hd.w, s);
        yp[i * 128] = s;
    }
}

extern "C" void kernel_launch(void* const* d_in, const int* in_sizes, int n_in,
                              void* d_out, int out_size, void* d_ws, size_t ws_size,
                              hipStream_t stream) {
    const float* x  = (const float*)d_in[0];
    const float* A  = (const float*)d_in[1];
    const float* Wb = (const float*)d_in[2];
    const float* bb = (const float*)d_in[3];
    const float* Wc = (const float*)d_in[4];
    const float* bc = (const float*)d_in[5];
    const float* Wd = (const float*)d_in[6];
    const float* bd = (const float*)d_in[7];
    float* ws = (float*)d_ws;
    float* y  = (float*)d_out;

    kA_fused<<<512, 256, 0, stream>>>(x, A, Wb, bb, Wc, bc, Wd, bd, ws, y);
    kB_combine<<<32, 256, 0, stream>>>(ws);
    kC_update<<<512, 256, 0, stream>>>(ws, y);
}